// Round 1
// baseline (579.973 us; speedup 1.0000x reference)
//
#include <hip/hip_runtime.h>
#include <hip/hip_bf16.h>

// ---------------------------------------------------------------------------
// Swin window MSA, MI355X/gfx950.
// Sizes (fixed): B_WIN=1024 windows, N_TOK=64, EMBED=512, HEADS=16, HD=32,
// NUM_WINDOWS(mask)=256. bf16 MFMA compute, fp32 accumulate.
// ---------------------------------------------------------------------------

typedef unsigned short u16;
typedef __bf16 bx8 __attribute__((ext_vector_type(8)));
typedef float f4_t __attribute__((ext_vector_type(4)));

#define QKV_ELEMS 33554432ull        // 1024*16*64*32 per Q/K/V plane
#define SCALE 0.17677669529663687f   // 32^-0.5

static __device__ __forceinline__ u16 f2b(float f) {
    return __builtin_bit_cast(u16, (__bf16)f);
}

// ---- prep: W (K x N fp32) -> Wt (N x K bf16) ------------------------------
__global__ void wt_k(const float* __restrict__ W, u16* __restrict__ Wt,
                     int K, int N) {
    int idx = blockIdx.x * 256 + threadIdx.x;
    if (idx >= N * K) return;
    int n = idx / K, k = idx - n * K;
    Wt[idx] = f2b(W[(size_t)k * N + n]);
}

// ---- prep: bias_full[h][q][k] = bias_table[rel_index[q*64+k]][h] ----------
__global__ void bias_k(const float* __restrict__ bias_table,
                       const int* __restrict__ rel_index,
                       float* __restrict__ bias_full) {
    int idx = blockIdx.x * 256 + threadIdx.x;   // 16*4096
    int h = idx >> 12, rc = idx & 4095;
    bias_full[idx] = bias_table[rel_index[rc] * 16 + h];
}

// ---- GEMM: C = A @ Bt^T (+bias). 128x128 tile, 4 waves, 4x4 MFMA/wave -----
// MODE 0: A fp32 (x), epilogue scatters bf16 into QKV planes [w][h][tok][d]
// MODE 1: A bf16 (attn out), epilogue writes fp32 d_out rows
template <int MODE>
__global__ __launch_bounds__(256) void gemm_k(
    const void* __restrict__ Av, const u16* __restrict__ Bt,
    const float* __restrict__ bias, void* __restrict__ Out, int K) {
    const int tid  = threadIdx.x;
    const int wave = tid >> 6, lane = tid & 63;
    const int quad = lane >> 4, l16 = lane & 15;
    const int wm = wave >> 1, wn = wave & 1;
    const int m0 = blockIdx.y * 128, n0 = blockIdx.x * 128;
    const int N = gridDim.x * 128;

    __shared__ alignas(16) u16 a_s[128 * 40];  // pad 40: <=2-way LDS aliasing
    __shared__ alignas(16) u16 b_s[128 * 40];

    f4_t acc[4][4];
#pragma unroll
    for (int i = 0; i < 4; ++i)
#pragma unroll
        for (int j = 0; j < 4; ++j) acc[i][j] = (f4_t){0.f, 0.f, 0.f, 0.f};

    for (int kt = 0; kt < K; kt += 32) {
        if (MODE == 0) {  // fp32 A -> cvt -> LDS
            const float* A = (const float*)Av;
#pragma unroll
            for (int r = 0; r < 4; ++r) {
                int f = tid + 256 * r;              // 1024 float4s
                int row = f >> 3, c4 = (f & 7) * 4;
                float4 v = *(const float4*)(A + (size_t)(m0 + row) * K + kt + c4);
                ushort4 p;
                p.x = f2b(v.x); p.y = f2b(v.y); p.z = f2b(v.z); p.w = f2b(v.w);
                *(ushort4*)&a_s[row * 40 + c4] = p;
            }
        } else {          // bf16 A -> LDS
            const u16* A = (const u16*)Av;
#pragma unroll
            for (int r = 0; r < 2; ++r) {
                int u = tid + 256 * r;              // 512 uint4s
                int row = u >> 2, c8 = (u & 3) * 8;
                uint4 v = *(const uint4*)(A + (size_t)(m0 + row) * K + kt + c8);
                *(uint4*)&a_s[row * 40 + c8] = v;
            }
        }
#pragma unroll
        for (int r = 0; r < 2; ++r) {               // B tile (Bt is N x K)
            int u = tid + 256 * r;
            int row = u >> 2, c8 = (u & 3) * 8;
            uint4 v = *(const uint4*)(Bt + (size_t)(n0 + row) * K + kt + c8);
            *(uint4*)&b_s[row * 40 + c8] = v;
        }
        __syncthreads();

        bx8 af[4], bfr[4];
#pragma unroll
        for (int mt = 0; mt < 4; ++mt)
            af[mt] = *(const bx8*)&a_s[(wm * 64 + mt * 16 + l16) * 40 + quad * 8];
#pragma unroll
        for (int nt = 0; nt < 4; ++nt)
            bfr[nt] = *(const bx8*)&b_s[(wn * 64 + nt * 16 + l16) * 40 + quad * 8];
#pragma unroll
        for (int mt = 0; mt < 4; ++mt)
#pragma unroll
            for (int nt = 0; nt < 4; ++nt)
                acc[mt][nt] = __builtin_amdgcn_mfma_f32_16x16x32_bf16(
                    af[mt], bfr[nt], acc[mt][nt], 0, 0, 0);
        __syncthreads();
    }

    if (MODE == 0) {
        u16* qkv = (u16*)Out;
#pragma unroll
        for (int mt = 0; mt < 4; ++mt)
#pragma unroll
            for (int nt = 0; nt < 4; ++nt)
#pragma unroll
                for (int i = 0; i < 4; ++i) {
                    int r = m0 + wm * 64 + mt * 16 + quad * 4 + i;
                    int c = n0 + wn * 64 + nt * 16 + l16;
                    float v = acc[mt][nt][i] + bias[c];
                    int w = r >> 6, tok = r & 63;
                    int h = c / 96, rr = c - h * 96;
                    int which = rr >> 5, dd = rr & 31;
                    qkv[(size_t)which * QKV_ELEMS +
                        ((size_t)((w * 16 + h) * 64 + tok)) * 32 + dd] = f2b(v);
                }
    } else {
        float* Of = (float*)Out;
#pragma unroll
        for (int mt = 0; mt < 4; ++mt)
#pragma unroll
            for (int nt = 0; nt < 4; ++nt)
#pragma unroll
                for (int i = 0; i < 4; ++i) {
                    int r = m0 + wm * 64 + mt * 16 + quad * 4 + i;
                    int c = n0 + wn * 64 + nt * 16 + l16;
                    Of[(size_t)r * N + c] = acc[mt][nt][i] + bias[c];
                }
    }
}

// ---- attention: 1 block per (window, head), 4 waves -----------------------
__global__ __launch_bounds__(256) void attn_k(
    const u16* __restrict__ qkv, const float* __restrict__ mask,
    const float* __restrict__ biasf, u16* __restrict__ attn_out) {
    const int bx = blockIdx.x;
    const int w = bx >> 4, h = bx & 15;
    const int wmk = w & 255;  // mask window = b % 256
    const int tid = threadIdx.x;
    const int wave = tid >> 6, lane = tid & 63;
    const int quad = lane >> 4, l16 = lane & 15;

    __shared__ alignas(16) u16 q_s[64 * 40];
    __shared__ alignas(16) u16 k_s[64 * 40];
    __shared__ alignas(16) u16 vT[32 * 72];   // vT[d][tok]
    __shared__ float s_s[64 * 68];
    __shared__ alignas(16) u16 p_s[64 * 72];

    const size_t base = (size_t)((w << 4) + h) * 2048;  // 64*32 per (w,h)
    {
        int tok = tid >> 2, d0 = (tid & 3) * 8;
        uint4 qv = *(const uint4*)(qkv + base + tid * 8);
        *(uint4*)&q_s[tok * 40 + d0] = qv;
        uint4 kv = *(const uint4*)(qkv + QKV_ELEMS + base + tid * 8);
        *(uint4*)&k_s[tok * 40 + d0] = kv;
        uint4 vv = *(const uint4*)(qkv + 2 * QKV_ELEMS + base + tid * 8);
        const u16* pv = (const u16*)&vv;
#pragma unroll
        for (int j = 0; j < 8; ++j) vT[(d0 + j) * 72 + tok] = pv[j];
    }
    __syncthreads();

    // S = Q K^T * scale + bias + mask  (wave -> 16-row strip)
    {
        bx8 a = *(const bx8*)&q_s[(wave * 16 + l16) * 40 + quad * 8];
#pragma unroll
        for (int nt = 0; nt < 4; ++nt) {
            bx8 b = *(const bx8*)&k_s[(nt * 16 + l16) * 40 + quad * 8];
            f4_t acc = (f4_t){0.f, 0.f, 0.f, 0.f};
            acc = __builtin_amdgcn_mfma_f32_16x16x32_bf16(a, b, acc, 0, 0, 0);
#pragma unroll
            for (int i = 0; i < 4; ++i) {
                int r = wave * 16 + quad * 4 + i;
                int c = nt * 16 + l16;
                float s = acc[i] * SCALE + biasf[(h << 12) + (r << 6) + c] +
                          mask[((size_t)wmk * 64 + r) * 64 + c];
                s_s[r * 68 + c] = s;
            }
        }
    }
    __syncthreads();

    // row softmax: 4 threads per row, 16 cols each, shuffle-reduce
    {
        int row = tid >> 2, j = (tid & 3) * 16;
        float mx = -1e30f;
#pragma unroll
        for (int cc = 0; cc < 16; ++cc) mx = fmaxf(mx, s_s[row * 68 + j + cc]);
        mx = fmaxf(mx, __shfl_xor(mx, 1));
        mx = fmaxf(mx, __shfl_xor(mx, 2));
        float e[16], sum = 0.f;
#pragma unroll
        for (int cc = 0; cc < 16; ++cc) {
            e[cc] = __expf(s_s[row * 68 + j + cc] - mx);
            sum += e[cc];
        }
        sum += __shfl_xor(sum, 1);
        sum += __shfl_xor(sum, 2);
        float inv = 1.f / sum;
#pragma unroll
        for (int cc = 0; cc < 16; ++cc) p_s[row * 72 + j + cc] = f2b(e[cc] * inv);
    }
    __syncthreads();

    // O = P V ; write bf16 [tok][h*32+d] rows for proj GEMM
    {
#pragma unroll
        for (int nt = 0; nt < 2; ++nt) {
            f4_t acc = (f4_t){0.f, 0.f, 0.f, 0.f};
#pragma unroll
            for (int ks = 0; ks < 2; ++ks) {
                bx8 a = *(const bx8*)&p_s[(wave * 16 + l16) * 72 + ks * 32 + quad * 8];
                bx8 b = *(const bx8*)&vT[(nt * 16 + l16) * 72 + ks * 32 + quad * 8];
                acc = __builtin_amdgcn_mfma_f32_16x16x32_bf16(a, b, acc, 0, 0, 0);
            }
#pragma unroll
            for (int i = 0; i < 4; ++i) {
                int r = wave * 16 + quad * 4 + i;
                int c = nt * 16 + l16;
                attn_out[((size_t)(w * 64 + r) << 9) + (h << 5) + c] = f2b(acc[i]);
            }
        }
    }
}

extern "C" void kernel_launch(void* const* d_in, const int* in_sizes, int n_in,
                              void* d_out, int out_size, void* d_ws,
                              size_t ws_size, hipStream_t stream) {
    const float* x      = (const float*)d_in[0];
    const float* mask   = (const float*)d_in[1];
    const float* qkv_w  = (const float*)d_in[2];
    const float* qkv_b  = (const float*)d_in[3];
    const float* proj_w = (const float*)d_in[4];
    const float* proj_b = (const float*)d_in[5];
    const float* bias_t = (const float*)d_in[6];
    const int*   rel    = (const int*)d_in[7];
    float* out = (float*)d_out;

    char* ws = (char*)d_ws;
    u16* Wt1 = (u16*)ws;      ws += (size_t)1536 * 512 * 2;   // qkv_w^T bf16
    u16* Wt2 = (u16*)ws;      ws += (size_t)512 * 512 * 2;    // proj_w^T bf16
    float* biasf = (float*)ws; ws += (size_t)16 * 64 * 64 * 4; // bias_full
    u16* qkv = (u16*)ws;      ws += 3 * QKV_ELEMS * 2;        // Q,K,V planes
    u16* attn = (u16*)ws;     ws += QKV_ELEMS * 2;            // attn out bf16

    wt_k<<<3072, 256, 0, stream>>>(qkv_w, Wt1, 512, 1536);
    wt_k<<<1024, 256, 0, stream>>>(proj_w, Wt2, 512, 512);
    bias_k<<<256, 256, 0, stream>>>(bias_t, rel, biasf);
    // QKV projection: M=65536, N=1536, K=512
    gemm_k<0><<<dim3(12, 512), 256, 0, stream>>>(x, Wt1, qkv_b, qkv, 512);
    // window attention: 1024 windows x 16 heads
    attn_k<<<16384, 256, 0, stream>>>(qkv, mask, biasf, attn);
    // output projection: M=65536, N=512, K=512
    gemm_k<1><<<dim3(4, 512), 256, 0, stream>>>(attn, Wt2, proj_b, out, 512);
}

// Round 2
// 572.126 us; speedup vs baseline: 1.0137x; 1.0137x over previous
//
#include <hip/hip_runtime.h>
#include <hip/hip_bf16.h>

// ---------------------------------------------------------------------------
// Swin window MSA, MI355X/gfx950.
// B_WIN=1024 windows, N_TOK=64, EMBED=512, HEADS=16, HD=32, mask windows=256.
// bf16 MFMA compute, fp32 accumulate. m97-style GEMM: 128x128 tile, BK=32,
// global_load_lds width-16 staging into unpadded LDS.
// ---------------------------------------------------------------------------

typedef unsigned short u16;
typedef __bf16 bx8 __attribute__((ext_vector_type(8)));
typedef float f4_t __attribute__((ext_vector_type(4)));

#define QKV_ELEMS 33554432ull        // 1024*16*64*32 per Q/K/V plane
#define SCALE 0.17677669529663687f   // 32^-0.5

static __device__ __forceinline__ u16 f2b(float f) {
    return __builtin_bit_cast(u16, (__bf16)f);
}

typedef const unsigned int __attribute__((address_space(1)))* gas_t;
typedef unsigned int __attribute__((address_space(3)))* las_t;
static __device__ __forceinline__ void glds16(const void* g, void* l) {
    __builtin_amdgcn_global_load_lds((gas_t)g, (las_t)l, 16, 0, 0);
}

// ---- prep: x fp32 -> bf16 (8 elems/thread) --------------------------------
__global__ void cvt_k(const float* __restrict__ X, u16* __restrict__ Xb) {
    size_t i = ((size_t)blockIdx.x * 256 + threadIdx.x) * 8;
    float4 v0 = *(const float4*)(X + i);
    float4 v1 = *(const float4*)(X + i + 4);
    ushort4 p0, p1;
    p0.x = f2b(v0.x); p0.y = f2b(v0.y); p0.z = f2b(v0.z); p0.w = f2b(v0.w);
    p1.x = f2b(v1.x); p1.y = f2b(v1.y); p1.z = f2b(v1.z); p1.w = f2b(v1.w);
    *(ushort4*)(Xb + i) = p0;
    *(ushort4*)(Xb + i + 4) = p1;
}

// ---- prep: W (K x N fp32) -> Wt (N x K bf16) ------------------------------
__global__ void wt_k(const float* __restrict__ W, u16* __restrict__ Wt,
                     int K, int N) {
    int idx = blockIdx.x * 256 + threadIdx.x;
    if (idx >= N * K) return;
    int n = idx / K, k = idx - n * K;
    Wt[idx] = f2b(W[(size_t)k * N + n]);
}

// ---- prep: bias_full[h][q][k] = bias_table[rel_index[q*64+k]][h] ----------
__global__ void bias_k(const float* __restrict__ bias_table,
                       const int* __restrict__ rel_index,
                       float* __restrict__ bias_full) {
    int idx = blockIdx.x * 256 + threadIdx.x;   // 16*4096
    int h = idx >> 12, rc = idx & 4095;
    bias_full[idx] = bias_table[rel_index[rc] * 16 + h];
}

// ---- GEMM: C = A @ Bt^T (+bias). A bf16 MxK, Bt bf16 NxK. -----------------
// 128x128 tile, 4 waves, 4x4 MFMA/wave, BK=32, global_load_lds staging.
// MODE 0: epilogue scatters bf16 into QKV planes [w][h][tok][d]
// MODE 1: epilogue writes fp32 rows (+bias)
template <int MODE>
__global__ __launch_bounds__(256) void gemm_k(
    const u16* __restrict__ A, const u16* __restrict__ Bt,
    const float* __restrict__ bias, void* __restrict__ Out, int K) {
    const int tid  = threadIdx.x;
    const int wave = tid >> 6, lane = tid & 63;
    const int quad = lane >> 4, l16 = lane & 15;
    const int wm = wave >> 1, wn = wave & 1;
    const int m0 = blockIdx.y * 128, n0 = blockIdx.x * 128;
    const int N = gridDim.x * 128;

    __shared__ alignas(16) u16 a_s[128 * 32];   // unpadded: glds layout
    __shared__ alignas(16) u16 b_s[128 * 32];

    // glds lane mapping: lane l -> row l/4, 16B chunk l%4 (within 16-row strip)
    const int lr = lane >> 2, lc = (lane & 3) * 8;
    const int w16 = wave * 16;

    f4_t acc[4][4];
#pragma unroll
    for (int i = 0; i < 4; ++i)
#pragma unroll
        for (int j = 0; j < 4; ++j) acc[i][j] = (f4_t){0.f, 0.f, 0.f, 0.f};

    for (int kt = 0; kt < K; kt += 32) {
        const u16* Ab = A + (size_t)m0 * K + kt;
        const u16* Bb = Bt + (size_t)n0 * K + kt;
        glds16(Ab + (size_t)(w16 + lr) * K + lc,      &a_s[w16 * 32]);
        glds16(Ab + (size_t)(w16 + 64 + lr) * K + lc, &a_s[(w16 + 64) * 32]);
        glds16(Bb + (size_t)(w16 + lr) * K + lc,      &b_s[w16 * 32]);
        glds16(Bb + (size_t)(w16 + 64 + lr) * K + lc, &b_s[(w16 + 64) * 32]);
        __syncthreads();

        bx8 af[4], bfr[4];
#pragma unroll
        for (int mt = 0; mt < 4; ++mt)
            af[mt] = *(const bx8*)&a_s[(wm * 64 + mt * 16 + l16) * 32 + quad * 8];
#pragma unroll
        for (int nt = 0; nt < 4; ++nt)
            bfr[nt] = *(const bx8*)&b_s[(wn * 64 + nt * 16 + l16) * 32 + quad * 8];
#pragma unroll
        for (int mt = 0; mt < 4; ++mt)
#pragma unroll
            for (int nt = 0; nt < 4; ++nt)
                acc[mt][nt] = __builtin_amdgcn_mfma_f32_16x16x32_bf16(
                    af[mt], bfr[nt], acc[mt][nt], 0, 0, 0);
        __syncthreads();
    }

    if (MODE == 0) {
        u16* qkv = (u16*)Out;
#pragma unroll
        for (int mt = 0; mt < 4; ++mt)
#pragma unroll
            for (int nt = 0; nt < 4; ++nt)
#pragma unroll
                for (int i = 0; i < 4; ++i) {
                    int r = m0 + wm * 64 + mt * 16 + quad * 4 + i;
                    int c = n0 + wn * 64 + nt * 16 + l16;
                    float v = acc[mt][nt][i] + bias[c];
                    int w = r >> 6, tok = r & 63;
                    int h = c / 96, rr = c - h * 96;
                    int which = rr >> 5, dd = rr & 31;
                    qkv[(size_t)which * QKV_ELEMS +
                        ((size_t)((w * 16 + h) * 64 + tok)) * 32 + dd] = f2b(v);
                }
    } else {
        float* Of = (float*)Out;
#pragma unroll
        for (int mt = 0; mt < 4; ++mt)
#pragma unroll
            for (int nt = 0; nt < 4; ++nt)
#pragma unroll
                for (int i = 0; i < 4; ++i) {
                    int r = m0 + wm * 64 + mt * 16 + quad * 4 + i;
                    int c = n0 + wn * 64 + nt * 16 + l16;
                    Of[(size_t)r * N + c] = acc[mt][nt][i] + bias[c];
                }
    }
}

// ---- attention: 1 block per (window, head), 4 waves -----------------------
__global__ __launch_bounds__(256) void attn_k(
    const u16* __restrict__ qkv, const float* __restrict__ mask,
    const float* __restrict__ biasf, u16* __restrict__ attn_out) {
    const int bx = blockIdx.x;
    const int w = bx >> 4, h = bx & 15;
    const int wmk = w & 255;  // mask window = b % 256
    const int tid = threadIdx.x;
    const int wave = tid >> 6, lane = tid & 63;
    const int quad = lane >> 4, l16 = lane & 15;

    __shared__ alignas(16) u16 q_s[64 * 40];
    __shared__ alignas(16) u16 k_s[64 * 40];
    __shared__ alignas(16) u16 vT[32 * 72];   // vT[d][tok]
    __shared__ float s_s[64 * 68];
    __shared__ alignas(16) u16 p_s[64 * 72];

    const size_t base = (size_t)((w << 4) + h) * 2048;  // 64*32 per (w,h)
    {
        int tok = tid >> 2, d0 = (tid & 3) * 8;
        uint4 qv = *(const uint4*)(qkv + base + tid * 8);
        *(uint4*)&q_s[tok * 40 + d0] = qv;
        uint4 kv = *(const uint4*)(qkv + QKV_ELEMS + base + tid * 8);
        *(uint4*)&k_s[tok * 40 + d0] = kv;
        uint4 vv = *(const uint4*)(qkv + 2 * QKV_ELEMS + base + tid * 8);
        const u16* pv = (const u16*)&vv;
#pragma unroll
        for (int j = 0; j < 8; ++j) vT[(d0 + j) * 72 + tok] = pv[j];
    }
    __syncthreads();

    // S = Q K^T * scale + bias + mask  (wave -> 16-row strip)
    {
        bx8 a = *(const bx8*)&q_s[(wave * 16 + l16) * 40 + quad * 8];
#pragma unroll
        for (int nt = 0; nt < 4; ++nt) {
            bx8 b = *(const bx8*)&k_s[(nt * 16 + l16) * 40 + quad * 8];
            f4_t acc = (f4_t){0.f, 0.f, 0.f, 0.f};
            acc = __builtin_amdgcn_mfma_f32_16x16x32_bf16(a, b, acc, 0, 0, 0);
#pragma unroll
            for (int i = 0; i < 4; ++i) {
                int r = wave * 16 + quad * 4 + i;
                int c = nt * 16 + l16;
                float s = acc[i] * SCALE + biasf[(h << 12) + (r << 6) + c] +
                          mask[((size_t)wmk * 64 + r) * 64 + c];
                s_s[r * 68 + c] = s;
            }
        }
    }
    __syncthreads();

    // row softmax: 4 threads per row, 16 cols each, shuffle-reduce
    {
        int row = tid >> 2, j = (tid & 3) * 16;
        float mx = -1e30f;
#pragma unroll
        for (int cc = 0; cc < 16; ++cc) mx = fmaxf(mx, s_s[row * 68 + j + cc]);
        mx = fmaxf(mx, __shfl_xor(mx, 1));
        mx = fmaxf(mx, __shfl_xor(mx, 2));
        float e[16], sum = 0.f;
#pragma unroll
        for (int cc = 0; cc < 16; ++cc) {
            e[cc] = __expf(s_s[row * 68 + j + cc] - mx);
            sum += e[cc];
        }
        sum += __shfl_xor(sum, 1);
        sum += __shfl_xor(sum, 2);
        float inv = 1.f / sum;
#pragma unroll
        for (int cc = 0; cc < 16; ++cc) p_s[row * 72 + j + cc] = f2b(e[cc] * inv);
    }
    __syncthreads();

    // O = P V ; write bf16 [tok][h*32+d] rows for proj GEMM
    {
#pragma unroll
        for (int nt = 0; nt < 2; ++nt) {
            f4_t acc = (f4_t){0.f, 0.f, 0.f, 0.f};
#pragma unroll
            for (int ks = 0; ks < 2; ++ks) {
                bx8 a = *(const bx8*)&p_s[(wave * 16 + l16) * 72 + ks * 32 + quad * 8];
                bx8 b = *(const bx8*)&vT[(nt * 16 + l16) * 72 + ks * 32 + quad * 8];
                acc = __builtin_amdgcn_mfma_f32_16x16x32_bf16(a, b, acc, 0, 0, 0);
            }
#pragma unroll
            for (int i = 0; i < 4; ++i) {
                int r = wave * 16 + quad * 4 + i;
                int c = nt * 16 + l16;
                attn_out[((size_t)(w * 64 + r) << 9) + (h << 5) + c] = f2b(acc[i]);
            }
        }
    }
}

extern "C" void kernel_launch(void* const* d_in, const int* in_sizes, int n_in,
                              void* d_out, int out_size, void* d_ws,
                              size_t ws_size, hipStream_t stream) {
    const float* x      = (const float*)d_in[0];
    const float* mask   = (const float*)d_in[1];
    const float* qkv_w  = (const float*)d_in[2];
    const float* qkv_b  = (const float*)d_in[3];
    const float* proj_w = (const float*)d_in[4];
    const float* proj_b = (const float*)d_in[5];
    const float* bias_t = (const float*)d_in[6];
    const int*   rel    = (const int*)d_in[7];
    float* out = (float*)d_out;

    char* ws = (char*)d_ws;
    u16* Wt1 = (u16*)ws;      ws += (size_t)1536 * 512 * 2;   // qkv_w^T bf16
    u16* Wt2 = (u16*)ws;      ws += (size_t)512 * 512 * 2;    // proj_w^T bf16
    float* biasf = (float*)ws; ws += (size_t)16 * 64 * 64 * 4; // bias_full
    u16* qkv = (u16*)ws;      ws += 3 * QKV_ELEMS * 2;        // Q,K,V planes
    u16* attn = (u16*)ws;     ws += QKV_ELEMS * 2;            // attn out bf16
    u16* xb = attn;  // alias: x_bf16 used only before attn_out is written

    cvt_k<<<16384, 256, 0, stream>>>(x, xb);   // 65536*512 / (256*8)
    wt_k<<<3072, 256, 0, stream>>>(qkv_w, Wt1, 512, 1536);
    wt_k<<<1024, 256, 0, stream>>>(proj_w, Wt2, 512, 512);
    bias_k<<<256, 256, 0, stream>>>(bias_t, rel, biasf);
    // QKV projection: M=65536, N=1536, K=512
    gemm_k<0><<<dim3(12, 512), 256, 0, stream>>>(xb, Wt1, qkv_b, qkv, 512);
    // window attention: 1024 windows x 16 heads
    attn_k<<<16384, 256, 0, stream>>>(qkv, mask, biasf, attn);
    // output projection: M=65536, N=512, K=512
    gemm_k<1><<<dim3(4, 512), 256, 0, stream>>>(attn, Wt2, proj_b, out, 512);
}

// Round 4
// 542.723 us; speedup vs baseline: 1.0686x; 1.0542x over previous
//
#include <hip/hip_runtime.h>
#include <hip/hip_bf16.h>

// ---------------------------------------------------------------------------
// Swin window MSA, MI355X/gfx950.
// B_WIN=1024 windows, N_TOK=64, EMBED=512, HEADS=16, HD=32, mask windows=256.
// bf16 MFMA compute, fp32 accumulate. m97-style GEMMs (128x128 tile, BK=32,
// global_load_lds width-16). All epilogues LDS-restaged so global stores are
// 16 B/lane fully-coalesced (fixes write-allocate RMW overfetch seen in R2:
// FETCH was ideal+WRITE_SIZE).
// R4 fix: MODE 1 store loop was j<2 (half tile) -> j<4.
// qkv planes: [which][w][h][tok][d]. attn out: head-blocked [h][w][tok][d].
// ---------------------------------------------------------------------------

typedef unsigned short u16;
typedef __bf16 bx8 __attribute__((ext_vector_type(8)));
typedef float f4_t __attribute__((ext_vector_type(4)));

#define QKV_ELEMS 33554432ull        // 1024*16*64*32 per Q/K/V plane
#define SCALE 0.17677669529663687f   // 32^-0.5

static __device__ __forceinline__ u16 f2b(float f) {
    return __builtin_bit_cast(u16, (__bf16)f);
}

typedef const unsigned int __attribute__((address_space(1)))* gas_t;
typedef unsigned int __attribute__((address_space(3)))* las_t;
static __device__ __forceinline__ void glds16(const void* g, void* l) {
    __builtin_amdgcn_global_load_lds((gas_t)g, (las_t)l, 16, 0, 0);
}

// ---- prep: x fp32 -> bf16 (8 elems/thread) --------------------------------
__global__ void cvt_k(const float* __restrict__ X, u16* __restrict__ Xb) {
    size_t i = ((size_t)blockIdx.x * 256 + threadIdx.x) * 8;
    float4 v0 = *(const float4*)(X + i);
    float4 v1 = *(const float4*)(X + i + 4);
    ushort4 p0, p1;
    p0.x = f2b(v0.x); p0.y = f2b(v0.y); p0.z = f2b(v0.z); p0.w = f2b(v0.w);
    p1.x = f2b(v1.x); p1.y = f2b(v1.y); p1.z = f2b(v1.z); p1.w = f2b(v1.w);
    *(ushort4*)(Xb + i) = p0;
    *(ushort4*)(Xb + i + 4) = p1;
}

// ---- prep: W (K x N fp32) -> Wt (N x K bf16) ------------------------------
__global__ void wt_k(const float* __restrict__ W, u16* __restrict__ Wt,
                     int K, int N) {
    int idx = blockIdx.x * 256 + threadIdx.x;
    if (idx >= N * K) return;
    int n = idx / K, k = idx - n * K;
    Wt[idx] = f2b(W[(size_t)k * N + n]);
}

// ---- prep: bias_full[h][q][k] = bias_table[rel_index[q*64+k]][h] ----------
__global__ void bias_k(const float* __restrict__ bias_table,
                       const int* __restrict__ rel_index,
                       float* __restrict__ bias_full) {
    int idx = blockIdx.x * 256 + threadIdx.x;   // 16*4096
    int h = idx >> 12, rc = idx & 4095;
    bias_full[idx] = bias_table[rel_index[rc] * 16 + h];
}

// ---- GEMM: C = A @ Bt^T (+bias). Bt bf16 NxK. -----------------------------
// 128x128 tile, 4 waves, 4x4 MFMA/wave, BK=32, global_load_lds staging.
// MODE 0: A = xb row-major MxK; epilogue -> QKV planes, coalesced uint4.
// MODE 1: A = attn head-blocked [h][w][tok][32]; epilogue -> fp32 rows (N=512).
template <int MODE>
__global__ __launch_bounds__(256) void gemm_k(
    const u16* __restrict__ A, const u16* __restrict__ Bt,
    const float* __restrict__ bias, void* __restrict__ Out, int K) {
    const int tid  = threadIdx.x;
    const int wave = tid >> 6, lane = tid & 63;
    const int quad = lane >> 4, l16 = lane & 15;
    const int wm = wave >> 1, wn = wave & 1;
    const int m0 = blockIdx.y * 128, n0 = blockIdx.x * 128;

    __shared__ alignas(16) char smem[17408];
    u16* a_s = (u16*)smem;            // 128*32 bf16 = 8 KB
    u16* b_s = (u16*)(smem + 8192);   // 128*32 bf16 = 8 KB

    // glds lane mapping: lane l -> row l/4, 16B chunk l%4 (16-row strip/wave)
    const int lr = lane >> 2, lc = (lane & 3) * 8;
    const int w16 = wave * 16;

    f4_t acc[4][4];
#pragma unroll
    for (int i = 0; i < 4; ++i)
#pragma unroll
        for (int j = 0; j < 4; ++j) acc[i][j] = (f4_t){0.f, 0.f, 0.f, 0.f};

    for (int kt = 0; kt < K; kt += 32) {
        if (MODE == 0) {
            const u16* Ab = A + (size_t)m0 * K + kt;
            glds16(Ab + (size_t)(w16 + lr) * K + lc,      &a_s[w16 * 32]);
            glds16(Ab + (size_t)(w16 + 64 + lr) * K + lc, &a_s[(w16 + 64) * 32]);
        } else {
            // head-blocked: plane hk = kt/32, window w0 = m0/64 (+1 for 2nd 64)
            const u16* Ab = A + (((size_t)(kt >> 5) * 1024 + (m0 >> 6)) << 11);
            glds16(Ab + ((w16 + lr) << 5) + lc,        &a_s[w16 * 32]);
            glds16(Ab + 2048 + ((w16 + lr) << 5) + lc, &a_s[(w16 + 64) * 32]);
        }
        const u16* Bb = Bt + (size_t)n0 * K + kt;
        glds16(Bb + (size_t)(w16 + lr) * K + lc,      &b_s[w16 * 32]);
        glds16(Bb + (size_t)(w16 + 64 + lr) * K + lc, &b_s[(w16 + 64) * 32]);
        __syncthreads();

        bx8 af[4], bfr[4];
#pragma unroll
        for (int mt = 0; mt < 4; ++mt)
            af[mt] = *(const bx8*)&a_s[(wm * 64 + mt * 16 + l16) * 32 + quad * 8];
#pragma unroll
        for (int nt = 0; nt < 4; ++nt)
            bfr[nt] = *(const bx8*)&b_s[(wn * 64 + nt * 16 + l16) * 32 + quad * 8];
#pragma unroll
        for (int mt = 0; mt < 4; ++mt)
#pragma unroll
            for (int nt = 0; nt < 4; ++nt)
                acc[mt][nt] = __builtin_amdgcn_mfma_f32_16x16x32_bf16(
                    af[mt], bfr[nt], acc[mt][nt], 0, 0, 0);
        __syncthreads();
    }

    float bv[4];
#pragma unroll
    for (int nt = 0; nt < 4; ++nt) bv[nt] = bias[n0 + wn * 64 + nt * 16 + l16];

    if (MODE == 0) {
        u16* c_s = (u16*)smem;        // [64][136] bf16 (pad: bank-clean)
        u16* qkv = (u16*)Out;
        const int g = tid >> 6, s = tid & 63;
        const int cgb = n0 + g * 32;           // 32-aligned, 96=3*32 => 1 group
        const int h = cgb / 96, rr = cgb - h * 96;
        const int which = rr >> 5;
#pragma unroll
        for (int p = 0; p < 2; ++p) {          // half-tile = one window
            if (wm == p) {
#pragma unroll
                for (int mt = 0; mt < 4; ++mt)
#pragma unroll
                    for (int nt = 0; nt < 4; ++nt)
#pragma unroll
                        for (int i = 0; i < 4; ++i)
                            c_s[(mt * 16 + quad * 4 + i) * 136 +
                                wn * 64 + nt * 16 + l16] =
                                f2b(acc[mt][nt][i] + bv[nt]);
            }
            __syncthreads();
            const int w = (m0 >> 6) + p;
            u16* dst = qkv + (size_t)which * QKV_ELEMS +
                       ((size_t)((w << 4) + h) << 11);
#pragma unroll
            for (int j = 0; j < 4; ++j) {
                int idx = s + 64 * j;          // uint4 index in 64x32 chunk
                int tok = idx >> 2, d8 = (idx & 3) * 8;
                uint4 v = *(const uint4*)&c_s[tok * 136 + g * 32 + d8];
                *(uint4*)(dst + idx * 8) = v;  // 1024 B/wave contiguous
            }
            __syncthreads();
        }
    } else {
        float* c_sf = (float*)smem;   // [32][136] fp32
        float* Of = (float*)Out;
#pragma unroll
        for (int p = 0; p < 4; ++p) {          // 32-row passes
            if (wm == (p >> 1)) {
                const int mtb = (p & 1) * 2;
#pragma unroll
                for (int mt2 = 0; mt2 < 2; ++mt2)
#pragma unroll
                    for (int nt = 0; nt < 4; ++nt)
#pragma unroll
                        for (int i = 0; i < 4; ++i)
                            c_sf[(mt2 * 16 + quad * 4 + i) * 136 +
                                 wn * 64 + nt * 16 + l16] =
                                acc[mtb + mt2][nt][i] + bv[nt];
            }
            __syncthreads();
#pragma unroll
            for (int j = 0; j < 4; ++j) {      // 1024 float4 = full 32x128 tile
                int fl = tid + 256 * j;
                int row = fl >> 5, c4 = (fl & 31) * 4;
                float4 v = *(const float4*)&c_sf[row * 136 + c4];
                *(float4*)&Of[(size_t)(m0 + p * 32 + row) * 512 + n0 + c4] = v;
            }
            __syncthreads();
        }
    }
}

// ---- attention: 1 block per (window, head), 4 waves -----------------------
__global__ __launch_bounds__(256) void attn_k(
    const u16* __restrict__ qkv, const float* __restrict__ mask,
    const float* __restrict__ biasf, u16* __restrict__ attn_out) {
    const int bx = blockIdx.x;
    const int w = bx >> 4, h = bx & 15;
    const int wmk = w & 255;  // mask window = b % 256
    const int tid = threadIdx.x;
    const int wave = tid >> 6, lane = tid & 63;
    const int quad = lane >> 4, l16 = lane & 15;

    __shared__ alignas(16) u16 q_s[64 * 40];
    __shared__ alignas(16) u16 k_s[64 * 40];
    __shared__ alignas(16) u16 vT[32 * 72];   // vT[d][tok]
    __shared__ alignas(16) float s_s[64 * 68];
    __shared__ alignas(16) u16 p_s[64 * 72];

    const size_t base = (size_t)((w << 4) + h) * 2048;  // 64*32 per (w,h)
    {
        int tok = tid >> 2, d0 = (tid & 3) * 8;
        uint4 qv = *(const uint4*)(qkv + base + tid * 8);
        *(uint4*)&q_s[tok * 40 + d0] = qv;
        uint4 kv = *(const uint4*)(qkv + QKV_ELEMS + base + tid * 8);
        *(uint4*)&k_s[tok * 40 + d0] = kv;
        uint4 vv = *(const uint4*)(qkv + 2 * QKV_ELEMS + base + tid * 8);
        const u16* pv = (const u16*)&vv;
#pragma unroll
        for (int j = 0; j < 8; ++j) vT[(d0 + j) * 72 + tok] = pv[j];
    }
    __syncthreads();

    // S = Q K^T * scale + bias + mask  (wave -> 16-row strip)
    {
        bx8 a = *(const bx8*)&q_s[(wave * 16 + l16) * 40 + quad * 8];
#pragma unroll
        for (int nt = 0; nt < 4; ++nt) {
            bx8 b = *(const bx8*)&k_s[(nt * 16 + l16) * 40 + quad * 8];
            f4_t acc = (f4_t){0.f, 0.f, 0.f, 0.f};
            acc = __builtin_amdgcn_mfma_f32_16x16x32_bf16(a, b, acc, 0, 0, 0);
#pragma unroll
            for (int i = 0; i < 4; ++i) {
                int r = wave * 16 + quad * 4 + i;
                int c = nt * 16 + l16;
                float s = acc[i] * SCALE + biasf[(h << 12) + (r << 6) + c] +
                          mask[((size_t)wmk * 64 + r) * 64 + c];
                s_s[r * 68 + c] = s;
            }
        }
    }
    __syncthreads();

    // row softmax: 4 threads per row, 16 cols each, shuffle-reduce
    {
        int row = tid >> 2, j = (tid & 3) * 16;
        float mx = -1e30f;
#pragma unroll
        for (int cc = 0; cc < 16; ++cc) mx = fmaxf(mx, s_s[row * 68 + j + cc]);
        mx = fmaxf(mx, __shfl_xor(mx, 1));
        mx = fmaxf(mx, __shfl_xor(mx, 2));
        float e[16], sum = 0.f;
#pragma unroll
        for (int cc = 0; cc < 16; ++cc) {
            e[cc] = __expf(s_s[row * 68 + j + cc] - mx);
            sum += e[cc];
        }
        sum += __shfl_xor(sum, 1);
        sum += __shfl_xor(sum, 2);
        float inv = 1.f / sum;
#pragma unroll
        for (int cc = 0; cc < 16; ++cc) p_s[row * 72 + j + cc] = f2b(e[cc] * inv);
    }
    __syncthreads();   // also fences s_s reads; s_s reused as O stage below

    // O = P V ; restage -> head-blocked [h][w][tok][d], coalesced uint4
    {
        u16* os = (u16*)s_s;   // [64][40]
#pragma unroll
        for (int nt = 0; nt < 2; ++nt) {
            f4_t acc = (f4_t){0.f, 0.f, 0.f, 0.f};
#pragma unroll
            for (int ks = 0; ks < 2; ++ks) {
                bx8 a = *(const bx8*)&p_s[(wave * 16 + l16) * 72 + ks * 32 + quad * 8];
                bx8 b = *(const bx8*)&vT[(nt * 16 + l16) * 72 + ks * 32 + quad * 8];
                acc = __builtin_amdgcn_mfma_f32_16x16x32_bf16(a, b, acc, 0, 0, 0);
            }
#pragma unroll
            for (int i = 0; i < 4; ++i)
                os[(wave * 16 + quad * 4 + i) * 40 + nt * 16 + l16] =
                    f2b(acc[i]);
        }
        __syncthreads();
        int tok = tid >> 2, d8 = (tid & 3) * 8;
        uint4 v = *(const uint4*)&os[tok * 40 + d8];
        *(uint4*)(attn_out + ((((size_t)h << 10) + w) << 11) + tid * 8) = v;
    }
}

extern "C" void kernel_launch(void* const* d_in, const int* in_sizes, int n_in,
                              void* d_out, int out_size, void* d_ws,
                              size_t ws_size, hipStream_t stream) {
    const float* x      = (const float*)d_in[0];
    const float* mask   = (const float*)d_in[1];
    const float* qkv_w  = (const float*)d_in[2];
    const float* qkv_b  = (const float*)d_in[3];
    const float* proj_w = (const float*)d_in[4];
    const float* proj_b = (const float*)d_in[5];
    const float* bias_t = (const float*)d_in[6];
    const int*   rel    = (const int*)d_in[7];
    float* out = (float*)d_out;

    char* ws = (char*)d_ws;
    u16* Wt1 = (u16*)ws;      ws += (size_t)1536 * 512 * 2;   // qkv_w^T bf16
    u16* Wt2 = (u16*)ws;      ws += (size_t)512 * 512 * 2;    // proj_w^T bf16
    float* biasf = (float*)ws; ws += (size_t)16 * 64 * 64 * 4; // bias_full
    u16* qkv = (u16*)ws;      ws += 3 * QKV_ELEMS * 2;        // Q,K,V planes
    u16* attn = (u16*)ws;     ws += QKV_ELEMS * 2;            // attn out bf16
    u16* xb = attn;  // alias: x_bf16 used only before attn_out is written

    cvt_k<<<16384, 256, 0, stream>>>(x, xb);   // 65536*512 / (256*8)
    wt_k<<<3072, 256, 0, stream>>>(qkv_w, Wt1, 512, 1536);
    wt_k<<<1024, 256, 0, stream>>>(proj_w, Wt2, 512, 512);
    bias_k<<<256, 256, 0, stream>>>(bias_t, rel, biasf);
    // QKV projection: M=65536, N=1536, K=512
    gemm_k<0><<<dim3(12, 512), 256, 0, stream>>>(xb, Wt1, qkv_b, qkv, 512);
    // window attention: 1024 windows x 16 heads
    attn_k<<<16384, 256, 0, stream>>>(qkv, mask, biasf, attn);
    // output projection: M=65536, N=512, K=512
    gemm_k<1><<<dim3(4, 512), 256, 0, stream>>>(attn, Wt2, proj_b, out, 512);
}